// Round 12
// baseline (540.243 us; speedup 1.0000x reference)
//
#include <hip/hip_runtime.h>
#include <hip/hip_cooperative_groups.h>

#define N_NODES 50000
#define N_EDGES 1600000
#define D_FEAT 512
#define FILTERS 256
#define NUM_CLASSES 16
#define NXCD 8

typedef __bf16 bf16x8 __attribute__((ext_vector_type(8)));
typedef float f32x4 __attribute__((ext_vector_type(4)));
typedef _Float16 half4 __attribute__((ext_vector_type(4)));
typedef _Float16 f16x8 __attribute__((ext_vector_type(8)));

#define GLOAD_LDS16(g, l)                                                  \
  __builtin_amdgcn_global_load_lds(                                        \
      (const __attribute__((address_space(1))) unsigned int*)(g),          \
      (__attribute__((address_space(3))) unsigned int*)(l), 16, 0, 0)

// ---------------------------------------------------------------------------
// hist8 + W1 split (r11-verified). Sub-histogram slot derived from EDGE id
// (x = (e>>8)&7) so hist and the fused fill agree on per-dst ordering.
// ---------------------------------------------------------------------------
__global__ __launch_bounds__(256) void hist8_kernel(
    const int* __restrict__ edst, int* __restrict__ deg8,
    const float* __restrict__ W1, __bf16* __restrict__ Wth,
    __bf16* __restrict__ Wtl) {
  const int e = blockIdx.x * 256 + threadIdx.x;
  if (e < D_FEAT * FILTERS) {  // W1 split: [512,256] fp32 -> hi/lo bf16^T
    const float v = W1[e];
    const int k = e >> 8;
    const int n = e & 255;
    const __bf16 h = (__bf16)v;
    Wth[n * D_FEAT + k] = h;
    Wtl[n * D_FEAT + k] = (__bf16)(v - (float)h);
  }
  if (e >= N_EDGES) return;
  const int x = (e >> 8) & (NXCD - 1);
  atomicAdd(&deg8[x * N_NODES + edst[e]], 1);
}

// ---------------------------------------------------------------------------
// Fused scan (cooperative, 196 blocks): per-block scan -> grid.sync ->
// in-block bsum prefix + row_ptr finalize + 8 per-slot cursor seed.
// ---------------------------------------------------------------------------
#define SCAN_NB 196
__global__ __launch_bounds__(256) void scan_coop_kernel(
    const int* __restrict__ deg8, int* __restrict__ row_ptr,
    int* __restrict__ bsum, int* __restrict__ cursor8) {
  cooperative_groups::grid_group grid = cooperative_groups::this_grid();
  __shared__ int s[256];
  __shared__ int wsum[4];
  const int i = blockIdx.x * 256 + threadIdx.x;

  int v = 0;
  if (i < N_NODES) {
#pragma unroll
    for (int x = 0; x < NXCD; ++x) v += deg8[x * N_NODES + i];
  }
  s[threadIdx.x] = v;
  __syncthreads();
  for (int off = 1; off < 256; off <<= 1) {
    const int t = (threadIdx.x >= off) ? s[threadIdx.x - off] : 0;
    __syncthreads();
    s[threadIdx.x] += t;
    __syncthreads();
  }
  const int excl = s[threadIdx.x] - v;
  if (threadIdx.x == 255) bsum[blockIdx.x] = s[255];
  grid.sync();

  // exclusive prefix of bsum[0..bid) computed in-block (bid <= 195 < 256)
  const int lane = threadIdx.x & 63;
  const int wave = threadIdx.x >> 6;
  int bv = (threadIdx.x < blockIdx.x) ? bsum[threadIdx.x] : 0;
#pragma unroll
  for (int off = 32; off >= 1; off >>= 1) bv += __shfl_xor(bv, off, 64);
  if (lane == 0) wsum[wave] = bv;
  __syncthreads();
  const int boff = wsum[0] + wsum[1] + wsum[2] + wsum[3];

  if (i < N_NODES) {
    int run = excl + boff;
    row_ptr[i] = run;
#pragma unroll
    for (int x = 0; x < NXCD; ++x) {
      cursor8[x * N_NODES + i] = run;
      run += deg8[x * N_NODES + i];
    }
  }
  if (i == 0) row_ptr[N_NODES] = N_EDGES;
}

// ---------------------------------------------------------------------------
// FAT kernel: gemm1 (blocks 0..781) CONCURRENT WITH fill (blocks 782..).
// r12 gemm1 reshape: BM=64 x BN=256 (grid.y gone) -> each X row loaded and
// hi/lo-converted exactly ONCE (per-thread conversions per k-step 32->8;
// X HBM traffic halved). B (0.5 MB) is L2-resident across blocks. MFMA
// sequence per output element unchanged -> bit-identical numerics.
// Fill branch is byte-identical to r11 (same 782-block offset, same
// e -> slot mapping as hist8).
// ---------------------------------------------------------------------------
#define G1_BLOCKS 782  // ceil(50000/64)
__global__ __launch_bounds__(256) void gemm1_fill_kernel(
    const float* __restrict__ A, const __bf16* __restrict__ Bh,
    const __bf16* __restrict__ Bl, _Float16* __restrict__ C,
    const int* __restrict__ esrc, const int* __restrict__ edst,
    const float* __restrict__ ew, int* __restrict__ cursor8,
    uint2* __restrict__ meta8) {
  __shared__ __bf16 sAh[64 * 32];
  __shared__ __bf16 sAl[64 * 32];
  __shared__ __bf16 sBh[256 * 32];
  __shared__ __bf16 sBl[256 * 32];

  if (blockIdx.x >= G1_BLOCKS) {
    // ---- fill branch: dst-sorted packed meta, slot-split cursor atomics
    const int e = (blockIdx.x - G1_BLOCKS) * 256 + threadIdx.x;
    if (e < N_EDGES) {
      const int x = (e >> 8) & (NXCD - 1);
      const int d = edst[e];
      const int pos = atomicAdd(&cursor8[x * N_NODES + d], 1);
      meta8[pos] = make_uint2((unsigned)esrc[e] | ((unsigned)(d & 15) << 16),
                              __float_as_uint(ew[e]));
    }
    return;
  }

  // ---- gemm1 branch: XW1 = X @ W1 (bf16x3), BM=64 x BN=256, fp16 out
  const int K = D_FEAT;
  const int tid = threadIdx.x;
  const int wave = tid >> 6;
  const int lane = tid & 63;
  const int wn = wave * 64;  // 4 waves cover N=256
  const int m0 = blockIdx.x * 64;

  const int arow = tid >> 2;        // 0..63
  const int aks = (tid & 3) * 8;    // 0,8,16,24
  int am = m0 + arow;
  if (am >= N_NODES) am = N_NODES - 1;
  const float* aptr = A + (size_t)am * K + aks;

  const int lr = lane >> 2;
  const int lc = (lane & 3) * 8;
  const int fm = lane & 15;
  const int fq = lane >> 4;

  f32x4 acc[4][4] = {};

  for (int k0 = 0; k0 < K; k0 += 32) {
    const float4* ap = (const float4*)(aptr + k0);
    const float4 a0 = ap[0], a1 = ap[1];

    __syncthreads();

#pragma unroll
    for (int i = 0; i < 4; ++i) {
      const int row = wn + i * 16;  // 4 waves x 4 x 16 = 256 rows
      GLOAD_LDS16(Bh + (size_t)(row + lr) * K + k0 + lc, sBh + row * 32);
      GLOAD_LDS16(Bl + (size_t)(row + lr) * K + k0 + lc, sBl + row * 32);
    }

    float va[8] = {a0.x, a0.y, a0.z, a0.w, a1.x, a1.y, a1.z, a1.w};
    __bf16 hh[8], ll[8];
#pragma unroll
    for (int i = 0; i < 8; ++i) {
      const __bf16 h = (__bf16)va[i];
      hh[i] = h;
      ll[i] = (__bf16)(va[i] - (float)h);
    }
    *(bf16x8*)(sAh + arow * 32 + aks) = *(bf16x8*)&hh[0];
    *(bf16x8*)(sAl + arow * 32 + aks) = *(bf16x8*)&ll[0];

    __syncthreads();

    bf16x8 fah[4], fal[4], fbh[4], fbl[4];
#pragma unroll
    for (int t = 0; t < 4; ++t) {
      const int moff = (t * 16 + fm) * 32 + fq * 8;
      fah[t] = *(const bf16x8*)(sAh + moff);
      fal[t] = *(const bf16x8*)(sAl + moff);
      const int noff = (wn + t * 16 + fm) * 32 + fq * 8;
      fbh[t] = *(const bf16x8*)(sBh + noff);
      fbl[t] = *(const bf16x8*)(sBl + noff);
    }
#pragma unroll
    for (int i = 0; i < 4; ++i)
#pragma unroll
      for (int j = 0; j < 4; ++j)
        acc[i][j] = __builtin_amdgcn_mfma_f32_16x16x32_bf16(fah[i], fbh[j],
                                                            acc[i][j], 0, 0, 0);
#pragma unroll
    for (int i = 0; i < 4; ++i)
#pragma unroll
      for (int j = 0; j < 4; ++j)
        acc[i][j] = __builtin_amdgcn_mfma_f32_16x16x32_bf16(fah[i], fbl[j],
                                                            acc[i][j], 0, 0, 0);
#pragma unroll
    for (int i = 0; i < 4; ++i)
#pragma unroll
      for (int j = 0; j < 4; ++j)
        acc[i][j] = __builtin_amdgcn_mfma_f32_16x16x32_bf16(fal[i], fbh[j],
                                                            acc[i][j], 0, 0, 0);
  }

#pragma unroll
  for (int ti = 0; ti < 4; ++ti) {
#pragma unroll
    for (int r = 0; r < 4; ++r) {
      const int m = m0 + ti * 16 + fq * 4 + r;
      if (m < N_NODES) {
#pragma unroll
        for (int tj = 0; tj < 4; ++tj) {
          const int n = wn + tj * 16 + fm;
          C[(size_t)m * FILTERS + n] = (_Float16)acc[ti][tj][r];
        }
      }
    }
  }
}

// ---------------------------------------------------------------------------
// Fused gather1 + relu + gemm2 (r2-verified structure, ~154 us floor). One
// wave per node; one coalesced 8B meta load per 64-edge chunk; per-edge
// (src,w) via readlane -> SGPR (scalar gather base); 8 gathers in flight.
// ---------------------------------------------------------------------------
__global__ __launch_bounds__(256) void gather1_gemm2_kernel(
    const _Float16* __restrict__ xw1, const int* __restrict__ row_ptr,
    const uint2* __restrict__ meta8, const float* __restrict__ W2,
    _Float16* __restrict__ h2) {
  __shared__ float red[4][16][17];
  const int wave = threadIdx.x >> 6;
  const int lane = threadIdx.x & 63;
  const int node = blockIdx.x * 4 + wave;
  const int beg = row_ptr[node];
  const int end = row_ptr[node + 1];

  float acc[4] = {};
  const half4* __restrict__ xw1v = (const half4*)xw1;  // row stride = 64

  for (int c0 = beg; c0 < end; c0 += 64) {
    const int cnt = min(64, end - c0);
    const uint2 mv = meta8[c0 + ((lane < cnt) ? lane : 0)];

    for (int j = 0; j < cnt; j += 8) {
      int srcs[8];
      float ws[8];
#pragma unroll
      for (int u = 0; u < 8; ++u) {
        const int live = (j + u < cnt);
        const int l = live ? (j + u) : 0;
        srcs[u] = __builtin_amdgcn_readlane((int)mv.x, l) & 0xFFFF;
        const int wb = __builtin_amdgcn_readlane((int)mv.y, l);
        ws[u] = live ? __int_as_float(wb) : 0.f;
      }
      half4 v[8];
#pragma unroll
      for (int u = 0; u < 8; ++u)
        v[u] = xw1v[(unsigned)srcs[u] * 64u + (unsigned)lane];
#pragma unroll
      for (int u = 0; u < 8; ++u)
#pragma unroll
        for (int i = 0; i < 4; ++i)
          acc[i] = fmaf(ws[u], (float)v[u][i], acc[i]);
    }
  }

  float r[4];
#pragma unroll
  for (int i = 0; i < 4; ++i) r[i] = fmaxf(acc[i], 0.f);

  // gemm2 partials: lane's k = lane*4 + j (covers all 256 k across 64 lanes)
  float p[16] = {};
#pragma unroll
  for (int j = 0; j < 4; ++j) {
    const float4* wr = (const float4*)(W2 + (size_t)(lane * 4 + j) * NUM_CLASSES);
#pragma unroll
    for (int c4 = 0; c4 < 4; ++c4) {
      const float4 wv = wr[c4];
      p[c4 * 4 + 0] = fmaf(r[j], wv.x, p[c4 * 4 + 0]);
      p[c4 * 4 + 1] = fmaf(r[j], wv.y, p[c4 * 4 + 1]);
      p[c4 * 4 + 2] = fmaf(r[j], wv.z, p[c4 * 4 + 2]);
      p[c4 * 4 + 3] = fmaf(r[j], wv.w, p[c4 * 4 + 3]);
    }
  }

#pragma unroll
  for (int off = 32; off >= 16; off >>= 1)
#pragma unroll
    for (int i = 0; i < 16; ++i) p[i] += __shfl_xor(p[i], off, 64);

  if (lane < 16) {
#pragma unroll
    for (int i = 0; i < 16; ++i) red[wave][lane][i] = p[i];
  }
  if (lane < 16) {
    float sum = 0.f;
#pragma unroll
    for (int i = 0; i < 16; ++i) sum += red[wave][i][lane];
    h2[(size_t)node * NUM_CLASSES + lane] = (_Float16)sum;
  }
}

// ---------------------------------------------------------------------------
// Gather2 + softmax via MFMA. One wave per 16-dst tile. 64-edge chunks,
// depth-1 meta prefetch, two 32-row gathers + two MFMAs per iteration.
// dst-local from meta8 bits 16..19 (tiles are 16-aligned).
// ---------------------------------------------------------------------------
__global__ __launch_bounds__(256) void gather2_mfma_kernel(
    const _Float16* __restrict__ h2, const int* __restrict__ row_ptr,
    const uint2* __restrict__ meta8, float* __restrict__ out) {
  __shared__ _Float16 lds[4][16][72];  // per-wave slice
  const int wave = threadIdx.x >> 6;
  const int lane = threadIdx.x & 63;
  const int tile = blockIdx.x * 4 + wave;
  if (tile >= N_NODES / 16) return;
  const int t0 = tile * 16;
  const int beg = row_ptr[t0];
  const int end = row_ptr[t0 + 16];

  const int cls = lane & 15;   // class (N) / dst-local for A (M)
  const int kq = lane >> 4;    // k-octet
  const int erow = lane >> 1;  // staged edge 0..31
  const int part = lane & 1;   // class half for staging

  f32x4 acc = {0.f, 0.f, 0.f, 0.f};
  _Float16* myl = &lds[wave][0][0];

  if (beg < end) {
    const int last = end - 1;
    int e = beg + lane;
    uint2 m = meta8[(e <= last) ? e : last];
    float wv = (e <= last) ? __uint_as_float(m.y) : 0.f;

    for (int c0 = beg; c0 < end; c0 += 64) {
      // depth-1 prefetch of next chunk's meta
      uint2 mn = m;
      float wn = 0.f;
      const int c1 = c0 + 64;
      if (c1 < end) {
        const int en = c1 + lane;
        mn = meta8[(en <= last) ? en : last];
        wn = (en <= last) ? __uint_as_float(mn.y) : 0.f;
      }

      // stage 64 rows (two b128 gathers per lane, independent)
      const int se0 = __shfl((int)m.x, erow, 64) & 0xFFFF;
      const int se1 = __shfl((int)m.x, 32 + erow, 64) & 0xFFFF;
      const f16x8 r0 =
          *(const f16x8*)(h2 + (size_t)se0 * NUM_CLASSES + part * 8);
      const f16x8 r1 =
          *(const f16x8*)(h2 + (size_t)se1 * NUM_CLASSES + part * 8);

      // A-frags: Sel[m=dst-local][k=edge] = w_e * (dst_local_e == m)
      f16x8 a0, a1;
#pragma unroll
      for (int j = 0; j < 8; ++j) {
        const int ei = kq * 8 + j;
        const int p0 = __shfl((int)m.x, ei, 64);
        const float w0 = __shfl(wv, ei, 64);
        a0[j] = (((p0 >> 16) & 15) == cls) ? (_Float16)w0 : (_Float16)0.f;
        const int p1 = __shfl((int)m.x, 32 + ei, 64);
        const float w1 = __shfl(wv, 32 + ei, 64);
        a1[j] = (((p1 >> 16) & 15) == cls) ? (_Float16)w1 : (_Float16)0.f;
      }

      // transpose into wave-private LDS: [class][edge]
#pragma unroll
      for (int j = 0; j < 8; ++j) myl[(part * 8 + j) * 72 + erow] = r0[j];
#pragma unroll
      for (int j = 0; j < 8; ++j) myl[(part * 8 + j) * 72 + 32 + erow] = r1[j];

      // B-frags: B[k=edge][n=class] (contiguous b128 reads)
      const f16x8 b0 = *(const f16x8*)(myl + cls * 72 + kq * 8);
      const f16x8 b1 = *(const f16x8*)(myl + cls * 72 + 32 + kq * 8);

      acc = __builtin_amdgcn_mfma_f32_16x16x32_f16(a0, b0, acc, 0, 0, 0);
      acc = __builtin_amdgcn_mfma_f32_16x16x32_f16(a1, b1, acc, 0, 0, 0);

      m = mn;
      wv = wn;
    }
  }

  // softmax per dst (classes live across the quad's 16 lanes)
#pragma unroll
  for (int r = 0; r < 4; ++r) {
    const float a = acc[r];
    float mx = a;
#pragma unroll
    for (int off = 8; off >= 1; off >>= 1)
      mx = fmaxf(mx, __shfl_xor(mx, off, 16));
    const float ex = __expf(a - mx);
    float sm = ex;
#pragma unroll
    for (int off = 8; off >= 1; off >>= 1) sm += __shfl_xor(sm, off, 16);
    out[(size_t)(t0 + kq * 4 + r) * NUM_CLASSES + cls] = ex / sm;
  }
}

extern "C" void kernel_launch(void* const* d_in, const int* in_sizes, int n_in,
                              void* d_out, int out_size, void* d_ws,
                              size_t ws_size, hipStream_t stream) {
  const float* x = (const float*)d_in[0];
  const float* W1 = (const float*)d_in[1];
  const float* W2 = (const float*)d_in[2];
  const float* ew = (const float*)d_in[3];
  const int* esrc = (const int*)d_in[4];
  const int* edst = (const int*)d_in[5];
  float* out = (float*)d_out;

  _Float16* xw1 = (_Float16*)d_ws;                               // 25.6 MB
  _Float16* h2 = xw1 + (size_t)N_NODES * FILTERS;                // 1.6 MB
  int* row_ptr = (int*)(h2 + (size_t)N_NODES * NUM_CLASSES);     // 50001
  int* deg8 = row_ptr + (N_NODES + 1);                           // 8*50000
  int* cursor8 = deg8 + NXCD * N_NODES;                          // 8*50000
  uint2* meta8 = (uint2*)(((uintptr_t)(cursor8 + NXCD * N_NODES) + 15) &
                          ~(uintptr_t)15);                       // 12.8 MB
  __bf16* w1th = (__bf16*)(meta8 + N_EDGES);
  __bf16* w1tl = w1th + D_FEAT * FILTERS;
  int* bsum = (int*)(w1tl + D_FEAT * FILTERS);                   // 256 ints

  hipMemsetAsync(deg8, 0, NXCD * N_NODES * sizeof(int), stream);
  hist8_kernel<<<(N_EDGES + 255) / 256, 256, 0, stream>>>(edst, deg8, W1,
                                                          w1th, w1tl);

  void* sargs[] = {(void*)&deg8, (void*)&row_ptr, (void*)&bsum,
                   (void*)&cursor8};
  hipLaunchCooperativeKernel((const void*)scan_coop_kernel, dim3(SCAN_NB),
                             dim3(256), sargs, 0, stream);

  // gemm1 (782 blocks) || fill (6250 blocks) in one launch
  gemm1_fill_kernel<<<G1_BLOCKS + (N_EDGES + 255) / 256, 256, 0, stream>>>(
      x, w1th, w1tl, xw1, esrc, edst, ew, cursor8, meta8);

  gather1_gemm2_kernel<<<N_NODES / 4, 256, 0, stream>>>(xw1, row_ptr, meta8,
                                                        W2, h2);

  gather2_mfma_kernel<<<(N_NODES / 16 + 3) / 4, 256, 0, stream>>>(h2, row_ptr,
                                                                  meta8, out);
}